// Round 10
// baseline (203.490 us; speedup 1.0000x reference)
//
#include <hip/hip_runtime.h>
#include <hip/hip_bf16.h>

// ---------------------------------------------------------------------------
// GraphExpert: per-node expert MLPs (16 nodes, 2048 batch, 512 hid) + gating.
// fp32 global I/O, bf16 MFMA compute.
// R19: counted-vmcnt test on gemm2_256. R17 (same kernel, __syncthreads)
// = 41.2us / MfmaUtil 14.6%: the drain barrier killed the prefetch (m218:
// 8ph-with-drain0 ~ 1ph; counted vmcnt IS the gain). Change: K-loop sync ->
// raw s_barrier + per-wave "s_waitcnt vmcnt(8)" (STAGE = 8 VMEM ops/wave;
// retires cur tile, keeps next tile's 8 in flight ACROSS the barrier) +
// lgkmcnt(0)+s_barrier after MFMA phase (reads retired before re-stage).
// Everything else R17/R18-verbatim. prep / gemm1_sm / fallback untouched.
// ---------------------------------------------------------------------------

typedef __attribute__((ext_vector_type(8))) short bf16x8;   // 8 bf16 = 4 VGPRs
typedef __attribute__((ext_vector_type(4))) float f32x4;    // MFMA C/D frag

// workspace layout (bytes)
#define OFF_W1T  (0u)          // bf16 [16][512][512]  (8 MB)
#define OFF_W2T  (8388608u)    // bf16 [16][512][512]  (8 MB)
#define OFF_H    (16777216u)   // bf16 [2048][16][512] (33.55 MB)
#define OFF_PART (50331648u)   // fp32 [16][2048][16]  (2 MB)
#define OFF_PROB (52428800u)   // fp32 [2048][16]      (128 KB)
#define OFF_GB   (52559872u)   // bf16 [2048][16][512] (33.55 MB) — new path only
#define WS_NEED_NEW (86114304ull)

__device__ __forceinline__ void gl2lds16(const void* g, void* l) {
  __builtin_amdgcn_global_load_lds(
      (const __attribute__((address_space(1))) void*)g,
      (__attribute__((address_space(3))) void*)l, 16, 0, 0);
}

__device__ __forceinline__ void cvt16v(const float* __restrict__ src,
                                       bf16x8& lo, bf16x8& hi) {
  float f[16];
  *(float4*)(f + 0)  = *(const float4*)(src + 0);
  *(float4*)(f + 4)  = *(const float4*)(src + 4);
  *(float4*)(f + 8)  = *(const float4*)(src + 8);
  *(float4*)(f + 12) = *(const float4*)(src + 12);
  __hip_bfloat16 t[16];
#pragma unroll
  for (int e = 0; e < 16; e++) t[e] = __float2bfloat16(f[e]);
  lo = *(const bf16x8*)t;
  hi = *(const bf16x8*)(t + 8);
}

// block-id remap: the 4 nblk siblings sharing one A-strip sit at bids
// b, b+8, b+16, b+24 (same bid%8 -> same XCD) for L2 reuse of the A strip.
__device__ __forceinline__ void decode_bid(int bid, int& nblk, int& mblk, int& n) {
  int x8 = bid & 7;
  nblk = (bid >> 3) & 3;
  int pair = (bid >> 5) * 8 + x8; // 0..255
  mblk = pair >> 4;
  n = pair & 15;
}

// ============ PREP: convert_gate (bids<1024) + transpose (bids>=1024) ======
__global__ __launch_bounds__(256, 3) void prep_kernel(
    const float* __restrict__ graphs,
    const float* __restrict__ Wg,
    const float* __restrict__ W1, const float* __restrict__ W2,
    __hip_bfloat16* __restrict__ W1t, __hip_bfloat16* __restrict__ W2t,
    __hip_bfloat16* __restrict__ gb,
    float* __restrict__ partial) {
  __shared__ char smem[49664]; // cg: Aw 4x8256 @0, Bt @33024 (16x1040),
                               // acc staging reuses Bt area after k-loop.
                               // transpose: 9216 B @0.
  const int tid = threadIdx.x, lane = tid & 63, wave = tid >> 6;

  if (blockIdx.x >= 1024) {
    // ================= transpose path =================
    const int t = blockIdx.x - 1024;      // 0..2047
    const int bx = t & 63, by = t >> 6;   // bx 0..63, by 0..31
    const int ht = bx & 7, kt = bx >> 3;
    const int n = by & 15;
    const float* src = (by >> 4) ? W2 : W1;
    __hip_bfloat16* dst = (by >> 4) ? W2t : W1t;
    src += (size_t)n * 262144;
    dst += (size_t)n * 262144;
    const int hq4 = (tid & 15) * 4, kr = tid >> 4;
#pragma unroll
    for (int rr = 0; rr < 4; rr++) {
      const int kl = rr * 16 + kr;
      float4 v = *(const float4*)(src + (size_t)(kt * 64 + kl) * 512 + ht * 64 + hq4);
      __hip_bfloat16 t4[4] = {__float2bfloat16(v.x), __float2bfloat16(v.y),
                              __float2bfloat16(v.z), __float2bfloat16(v.w)};
#pragma unroll
      for (int i = 0; i < 4; i++)
        *(__hip_bfloat16*)(smem + (hq4 + i) * 144 + kl * 2) = t4[i];
    }
    __syncthreads();
    const int c8 = tid & 7, hr = tid >> 3;
#pragma unroll
    for (int rr = 0; rr < 2; rr++) {
      const int hl = rr * 32 + hr;
      bf16x8 v = *(const bf16x8*)(smem + hl * 144 + c8 * 16);
      *(bf16x8*)(dst + (size_t)(ht * 64 + hl) * 512 + kt * 64 + c8 * 8) = v;
    }
    return;
  }

  // ================= convert_gate path (full A prefetch) =================
  const int q = lane >> 4, l15 = lane & 15;
  const int n = blockIdx.x & 15, rb = blockIdx.x >> 4;
  char* Bt = smem + 33024;
  char* Aw = smem + wave * 8256;

  const int arow = lane >> 1, ahalf = (lane & 1) * 16;
  const float* Ag = graphs + (size_t)(rb * 32) * 8192 + n * 512 + wave * 128;

  // FULL prefetch: all 64 fp32 (16 float4) issued before Bt staging.
  float g[64];
  {
    const float* ap = Ag + (size_t)arow * 8192 + ahalf;
#pragma unroll
    for (int ks = 0; ks < 4; ks++)
#pragma unroll
      for (int j = 0; j < 4; j++)
        *(float4*)(g + ks * 16 + j * 4) = *(const float4*)(ap + ks * 32 + j * 4);
  }

  // Bt staging: Wg n-slice -> bf16, Bt[j][k] row stride 1040 B
#pragma unroll
  for (int i = 0; i < 2; i++) {
    int k = i * 256 + tid;
    const float* wr_ = Wg + (size_t)(n * 512 + k) * 16;
    float f[16];
    *(float4*)(f + 0)  = *(const float4*)(wr_ + 0);
    *(float4*)(f + 4)  = *(const float4*)(wr_ + 4);
    *(float4*)(f + 8)  = *(const float4*)(wr_ + 8);
    *(float4*)(f + 12) = *(const float4*)(wr_ + 12);
#pragma unroll
    for (int j = 0; j < 16; j++)
      *(__hip_bfloat16*)(Bt + j * 1040 + k * 2) = __float2bfloat16(f[j]);
  }
  __syncthreads();

  f32x4 acc[2] = {};
#pragma unroll
  for (int ks = 0; ks < 4; ks++) {
    const float* gc = g + ks * 16;
    __hip_bfloat16 t[16];
#pragma unroll
    for (int e = 0; e < 16; e++) t[e] = __float2bfloat16(gc[e]);
    bf16x8 lo = *(const bf16x8*)t, hi = *(const bf16x8*)(t + 8);
    const int c0 = ks * 4 + (lane & 1) * 2;
    const int rx = arow & 7;
    *(bf16x8*)(Aw + arow * 256 + ((c0 ^ rx) * 16)) = lo;
    *(bf16x8*)(Aw + arow * 256 + (((c0 + 1) ^ rx) * 16)) = hi;
    bf16x8 bv = *(const bf16x8*)(Bt + l15 * 1040 + (wave * 128 + ks * 32 + q * 8) * 2);
#pragma unroll
    for (int im = 0; im < 2; im++) {
      const int ar = im * 16 + l15;
      bf16x8 av = *(const bf16x8*)(Aw + ar * 256 + (((ks * 4 + q) ^ (ar & 7)) * 16));
      acc[im] = __builtin_amdgcn_mfma_f32_16x16x32_bf16(av, bv, acc[im], 0, 0, 0);
    }
  }
  __syncthreads();

  // acc staging into the (now dead) Bt area: per-wave 2 KB
#pragma unroll
  for (int im = 0; im < 2; im++)
#pragma unroll
    for (int r = 0; r < 4; r++)
      *(float*)(smem + 33024 + wave * 2048 + (im * 16 + q * 4 + r) * 64 + l15 * 4) = acc[im][r];

  // coalesced gb store
  __hip_bfloat16* gbase = gb + (size_t)(rb * 32) * 8192 + n * 512;
#pragma unroll
  for (int r = 0; r < 8; r++) {
    int u = r * 256 + tid;
    int row = u >> 6, cu = u & 63;
    int ch = (cu & 15) ^ (row & 7);
    bf16x8 v = *(const bf16x8*)(smem + (cu >> 4) * 8256 + row * 256 + ch * 16);
    *(bf16x8*)(gbase + (size_t)row * 8192 + cu * 8) = v;
  }
  __syncthreads();

#pragma unroll
  for (int i = 0; i < 2; i++) {
    int c = i * 256 + tid;
    int rrow = c >> 4, j = c & 15;
    float s = 0.f;
#pragma unroll
    for (int w = 0; w < 4; w++)
      s += *(const float*)(smem + 33024 + w * 2048 + rrow * 64 + j * 4);
    partial[((size_t)n * 2048 + rb * 32 + rrow) * 16 + j] = s;
  }
}

// ============ GEMM1 (bids<1024, pure gl2lds) + softmax (bids>=1024) ========
__global__ __launch_bounds__(256, 4) void gemm1_sm_kernel(
    const __hip_bfloat16* __restrict__ gbuf,
    const __hip_bfloat16* __restrict__ W1t,
    const float* __restrict__ b1,
    const float* __restrict__ partial,
    const float* __restrict__ bg,
    __hip_bfloat16* __restrict__ h,
    float* __restrict__ probs,
    float* __restrict__ probs_out) {
  __shared__ char smem[36864]; // A16K@0, B16K@16384; epi 4x9216@0
  const int tid = threadIdx.x, lane = tid & 63, wave = tid >> 6;

  if (blockIdx.x >= 1024) {
    // ================= softmax path (8 blocks) =================
    const int r = (blockIdx.x - 1024) * 256 + tid; // 0..2047
    float s[16];
#pragma unroll
    for (int j = 0; j < 16; j++) s[j] = 0.f;
    for (int nn = 0; nn < 16; nn++) {
      const float4* p = (const float4*)(partial + ((size_t)nn * 2048 + r) * 16);
#pragma unroll
      for (int c = 0; c < 4; c++) {
        float4 v = p[c];
        s[c * 4 + 0] += v.x; s[c * 4 + 1] += v.y;
        s[c * 4 + 2] += v.z; s[c * 4 + 3] += v.w;
      }
    }
    float mx = -1e30f;
#pragma unroll
    for (int j = 0; j < 16; j++) { s[j] += bg[j]; mx = fmaxf(mx, s[j]); }
    float sum = 0.f;
#pragma unroll
    for (int j = 0; j < 16; j++) { s[j] = __expf(s[j] - mx); sum += s[j]; }
    float inv = 1.f / sum;
#pragma unroll
    for (int j = 0; j < 16; j++) s[j] *= inv;
    float4* pw = (float4*)(probs + (size_t)r * 16);
    float4* ow = (float4*)(probs_out + (size_t)r * 16);
#pragma unroll
    for (int c = 0; c < 4; c++) {
      float4 v = make_float4(s[c*4], s[c*4+1], s[c*4+2], s[c*4+3]);
      pw[c] = v; ow[c] = v;
    }
    return;
  }

  // ================= gemm1 main path =================
  int nblk, mblk, n;
  decode_bid(blockIdx.x, nblk, mblk, n);
  const int wm = (wave >> 1) * 64, wn = (wave & 1) * 64;
  const int q = lane >> 4, l15 = lane & 15;
  const int lrow = lane >> 3, lcol = lane & 7;
  const int swz = (lcol ^ lrow) * 8;
  const int xr = l15 & 7;

  const __hip_bfloat16* Ag = gbuf + (size_t)(mblk * 128) * 8192 + n * 512;
  const __hip_bfloat16* Bg = W1t + (size_t)n * 262144 + (size_t)(nblk * 128) * 512;

  f32x4 acc[4][4] = {};
  for (int ks = 0; ks < 8; ks++) {
    const int k0 = ks * 64;
#pragma unroll
    for (int i = 0; i < 4; i++) {
      const int r = i * 32 + wave * 8 + lrow;
      gl2lds16(Ag + (size_t)r * 8192 + k0 + swz, smem + i * 4096 + wave * 1024 + lane * 16);
      gl2lds16(Bg + (size_t)r * 512 + k0 + swz,
               smem + 16384 + i * 4096 + wave * 1024 + lane * 16);
    }
    __syncthreads();
#pragma unroll
    for (int hh = 0; hh < 2; hh++) {
      const int co = ((q + hh * 4) ^ xr) * 16;
      bf16x8 av[4], bv[4];
#pragma unroll
      for (int im = 0; im < 4; im++)
        av[im] = *(const bf16x8*)(smem + (wm + im * 16 + l15) * 128 + co);
#pragma unroll
      for (int in = 0; in < 4; in++)
        bv[in] = *(const bf16x8*)(smem + 16384 + (wn + in * 16 + l15) * 128 + co);
#pragma unroll
      for (int im = 0; im < 4; im++)
#pragma unroll
        for (int in = 0; in < 4; in++)
          acc[im][in] = __builtin_amdgcn_mfma_f32_16x16x32_bf16(av[im], bv[in], acc[im][in], 0, 0, 0);
    }
    __syncthreads();
  }

  float bias[4];
#pragma unroll
  for (int in = 0; in < 4; in++)
    bias[in] = b1[n * 512 + nblk * 128 + wn + in * 16 + l15];
  char* epi = smem + wave * 9216;
#pragma unroll
  for (int im = 0; im < 4; im++)
#pragma unroll
    for (int in = 0; in < 4; in++)
#pragma unroll
      for (int r = 0; r < 4; r++) {
        float v = acc[im][in][r] + bias[in];
        v = fmaxf(v, 0.f);
        int rl = im * 16 + q * 4 + r;
        int cl = in * 16 + l15;
        *(__hip_bfloat16*)(epi + rl * 144 + cl * 2) = __float2bfloat16(v);
      }
  __syncthreads();
  __hip_bfloat16* Hg = h + (size_t)(mblk * 128 + wm) * 8192 + n * 512 + nblk * 128 + wn;
#pragma unroll
  for (int it = 0; it < 8; it++) {
    int rl = it * 8 + (lane >> 3);
    int cl = (lane & 7) * 8;
    bf16x8 v = *(const bf16x8*)(epi + rl * 144 + cl * 2);
    *(bf16x8*)(Hg + (size_t)rl * 8192 + cl) = v;
  }
}

// ======== GEMM2 256^2 double-buffered, COUNTED vmcnt (new path) ============
// 256 blocks x 512 threads (8 waves: 2m x 4n), BM=BN=256, BK=64.
// LDS 128 KiB: buf b at b*65536: A 256x64 bf16 (32K) @0, B @32768.
// Per K-tile: STAGE(next) -> s_waitcnt vmcnt(8) (cur's 8 loads done, next's
// 8 stay IN FLIGHT) -> raw s_barrier -> MFMA -> lgkmcnt(0) -> raw s_barrier.
__global__ __launch_bounds__(512, 2) void gemm2_256_kernel(
    const __hip_bfloat16* __restrict__ hbuf,
    const __hip_bfloat16* __restrict__ W2t,
    const float* __restrict__ b2,
    const float* __restrict__ probs,
    float* __restrict__ out) {
  __shared__ char smem[131072];
  const int tid = threadIdx.x, lane = tid & 63, wave = tid >> 6;
  // XCD-chunked decode: bijective for 256 blocks; XCD x gets 2 full nodes.
  const int wgid = (blockIdx.x & 7) * 32 + (blockIdx.x >> 3);
  const int n = wgid >> 4;
  const int inner = wgid & 15;
  const int mblk = inner >> 1, nblk2 = inner & 1;
  const int wm = (wave >> 2) * 128;   // 0 / 128
  const int wn = (wave & 3) * 64;     // 0..192
  const int q = lane >> 4, l15 = lane & 15;
  const int lrow = lane >> 3, lcol = lane & 7;
  const int swz = (lcol ^ lrow) * 8;  // pre-swizzled global chunk
  const int xr = l15 & 7;

  const __hip_bfloat16* Ag = hbuf + (size_t)(mblk * 256) * 8192 + n * 512;
  const __hip_bfloat16* Bg = W2t + (size_t)n * 262144 + (size_t)(nblk2 * 256) * 512;

  f32x4 acc[8][4] = {};

  // ---- STAGE tile (k0) into buffer b: 8 gl2lds per thread/wave ----
  auto STAGE = [&](int b, int k0) {
    char* Ab = smem + b * 65536;
    char* Bb = Ab + 32768;
#pragma unroll
    for (int i = 0; i < 4; i++) {
      const int r = i * 64 + wave * 8 + lrow;
      gl2lds16(Ag + (size_t)r * 8192 + k0 + swz, Ab + i * 8192 + wave * 1024 + lane * 16);
      gl2lds16(Bg + (size_t)r * 512 + k0 + swz, Bb + i * 8192 + wave * 1024 + lane * 16);
    }
  };

  STAGE(0, 0);                         // 8 VMEM in flight (tile 0)
  for (int kt = 0; kt < 8; kt++) {
    const int buf = kt & 1;
    if (kt < 7) {
      STAGE(buf ^ 1, (kt + 1) * 64);   // +8 -> 16 in flight
      asm volatile("s_waitcnt vmcnt(8)" ::: "memory");  // cur done; next flies
    } else {
      asm volatile("s_waitcnt vmcnt(0)" ::: "memory");  // last tile: drain
    }
    __builtin_amdgcn_s_barrier();      // all waves: cur tile fully staged
    const char* Ab = smem + buf * 65536;
    const char* Bb = Ab + 32768;
#pragma unroll
    for (int hh = 0; hh < 2; hh++) {
      const int co = ((q + hh * 4) ^ xr) * 16;
      bf16x8 av[8], bv[4];
#pragma unroll
      for (int im = 0; im < 8; im++)
        av[im] = *(const bf16x8*)(Ab + (wm + im * 16 + l15) * 128 + co);
#pragma unroll
      for (int in = 0; in < 4; in++)
        bv[in] = *(const bf16x8*)(Bb + (wn + in * 16 + l15) * 128 + co);
#pragma unroll
      for (int im = 0; im < 8; im++)
#pragma unroll
        for (int in = 0; in < 4; in++)
          acc[im][in] = __builtin_amdgcn_mfma_f32_16x16x32_bf16(av[im], bv[in], acc[im][in], 0, 0, 0);
    }
    asm volatile("s_waitcnt lgkmcnt(0)" ::: "memory"); // ds_reads retired
    __builtin_amdgcn_s_barrier();      // safe to re-stage this buffer
  }

  // ---- epilogue: bias + probs-weighted combine (sum over j = l15) ----
  float bias[4];
#pragma unroll
  for (int in = 0; in < 4; in++)
    bias[in] = b2[n * 512 + nblk2 * 256 + wn + in * 16 + l15];
  float* comb = (float*)smem; // [256][16] fp32 = 16 KB (staging LDS reused)
#pragma unroll
  for (int im = 0; im < 8; im++)
#pragma unroll
    for (int r = 0; r < 4; r++) {
      const int rl = wm + im * 16 + q * 4 + r; // block-local row 0..255
      float pv = probs[(size_t)(mblk * 256 + rl) * 16 + l15];
#pragma unroll
      for (int in = 0; in < 4; in++) {
        float v = (acc[im][in][r] + bias[in]) * pv;
        v += __shfl_xor(v, 1);
        v += __shfl_xor(v, 2);
        v += __shfl_xor(v, 4);
        v += __shfl_xor(v, 8);
        if (l15 == 0) comb[rl * 16 + (wn >> 4) + in] = v;
      }
    }
  __syncthreads();
#pragma unroll
  for (int rnd = 0; rnd < 2; rnd++) {
    const int idx = rnd * 512 + tid;
    const int row = idx >> 2, c4 = idx & 3;
    float4 v = *(const float4*)(comb + row * 16 + c4 * 4);
    *(float4*)(out + (size_t)(mblk * 256 + row) * 512 + n * 32 + nblk2 * 16 + c4 * 4) = v;
  }
}

// ----------- standalone kernels for the ws-fallback path (R11) -------------
__global__ __launch_bounds__(256) void transpose_kernel(
    const float* __restrict__ W1, const float* __restrict__ W2,
    __hip_bfloat16* __restrict__ W1t, __hip_bfloat16* __restrict__ W2t) {
  __shared__ char smem[9216];
  const int bx = blockIdx.x;
  const int ht = bx & 7, kt = bx >> 3;
  const int n = blockIdx.y & 15;
  const float* src = (blockIdx.y >> 4) ? W2 : W1;
  __hip_bfloat16* dst = (blockIdx.y >> 4) ? W2t : W1t;
  src += (size_t)n * 262144;
  dst += (size_t)n * 262144;
  const int tid = threadIdx.x;
  const int hq4 = (tid & 15) * 4, kr = tid >> 4;
#pragma unroll
  for (int rr = 0; rr < 4; rr++) {
    const int kl = rr * 16 + kr;
    float4 v = *(const float4*)(src + (size_t)(kt * 64 + kl) * 512 + ht * 64 + hq4);
    __hip_bfloat16 t4[4] = {__float2bfloat16(v.x), __float2bfloat16(v.y),
                            __float2bfloat16(v.z), __float2bfloat16(v.w)};
#pragma unroll
    for (int i = 0; i < 4; i++)
      *(__hip_bfloat16*)(smem + (hq4 + i) * 144 + kl * 2) = t4[i];
  }
  __syncthreads();
  const int c8 = tid & 7, hr = tid >> 3;
#pragma unroll
  for (int rr = 0; rr < 2; rr++) {
    const int hl = rr * 32 + hr;
    bf16x8 v = *(const bf16x8*)(smem + hl * 144 + c8 * 16);
    *(bf16x8*)(dst + (size_t)(ht * 64 + hl) * 512 + kt * 64 + c8 * 8) = v;
  }
}

__global__ void softmax_kernel(const float* __restrict__ partial,
                               const float* __restrict__ bg,
                               float* __restrict__ probs,
                               float* __restrict__ probs_out) {
  const int r = blockIdx.x * 256 + threadIdx.x;
  float s[16];
#pragma unroll
  for (int j = 0; j < 16; j++) s[j] = 0.f;
  for (int nn = 0; nn < 16; nn++) {
    const float4* p = (const float4*)(partial + ((size_t)nn * 2048 + r) * 16);
#pragma unroll
    for (int c = 0; c < 4; c++) {
      float4 v = p[c];
      s[c * 4 + 0] += v.x; s[c * 4 + 1] += v.y;
      s[c * 4 + 2] += v.z; s[c * 4 + 3] += v.w;
    }
  }
  float mx = -1e30f;
#pragma unroll
  for (int j = 0; j < 16; j++) { s[j] += bg[j]; mx = fmaxf(mx, s[j]); }
  float sum = 0.f;
#pragma unroll
  for (int j = 0; j < 16; j++) { s[j] = __expf(s[j] - mx); sum += s[j]; }
  float inv = 1.f / sum;
#pragma unroll
  for (int j = 0; j < 16; j++) s[j] *= inv;
  float4* pw = (float4*)(probs + (size_t)r * 16);
  float4* ow = (float4*)(probs_out + (size_t)r * 16);
#pragma unroll
  for (int c = 0; c < 4; c++) {
    float4 v = make_float4(s[c*4], s[c*4+1], s[c*4+2], s[c*4+3]);
    pw[c] = v; ow[c] = v;
  }
}

__global__ __launch_bounds__(256, 4) void gemm1_gate_kernel(
    const float* __restrict__ graphs,
    const __hip_bfloat16* __restrict__ W1t,
    const float* __restrict__ Wg,
    const float* __restrict__ b1,
    __hip_bfloat16* __restrict__ h,
    float* __restrict__ partial) {
  __shared__ char smem[36864];
  const int tid = threadIdx.x, lane = tid & 63, wave = tid >> 6;
  const int q = lane >> 4, l15 = lane & 15;

  if (blockIdx.x >= 1024) {
    const int gbid = blockIdx.x - 1024;
    const int n = gbid & 15, rb = gbid >> 4;
    char* Bt = smem + 8192;
#pragma unroll
    for (int i = 0; i < 2; i++) {
      int k = i * 256 + tid;
      const float* wr_ = Wg + (size_t)(n * 512 + k) * 16;
      float f[16];
      *(float4*)(f + 0)  = *(const float4*)(wr_ + 0);
      *(float4*)(f + 4)  = *(const float4*)(wr_ + 4);
      *(float4*)(f + 8)  = *(const float4*)(wr_ + 8);
      *(float4*)(f + 12) = *(const float4*)(wr_ + 12);
#pragma unroll
      for (int j = 0; j < 16; j++)
        *(__hip_bfloat16*)(Bt + j * 1040 + k * 2) = __float2bfloat16(f[j]);
    }
    __syncthreads();

    const int arow = lane >> 1, ahalf = (lane & 1) * 16;
    const float* Ag = graphs + (size_t)(rb * 32) * 8192 + n * 512 + wave * 128;
    char* Aw = smem + wave * 2048;

    f32x4 acc[2] = {};
    for (int ks = 0; ks < 4; ks++) {
      bf16x8 lo, hi;
      cvt16v(Ag + (size_t)arow * 8192 + ks * 32 + ahalf, lo, hi);
      char* d = Aw + arow * 64 + ahalf * 2;
      *(bf16x8*)d = lo;
      *(bf16x8*)(d + 16) = hi;
      bf16x8 bv = *(const bf16x8*)(Bt + l15 * 1040 + (wave * 128 + ks * 32 + q * 8) * 2);
#pragma unroll
      for (int im = 0; im < 2; im++) {
        bf16x8 av = *(const bf16x8*)(Aw + (im * 16 + l15) * 64 + q * 16);
        acc[im] = __builtin_amdgcn_mfma_f32_16x16x32_bf16(av, bv, acc[im], 0, 0, 0);
      }
    }
#pragma unroll
    for (int im = 0; im < 2; im++)
#pragma unroll
      for (int r = 0; r < 4; r++)
        *(float*)(smem + wave * 2048 + (im * 16 + q * 4 + r) * 64 + l15 * 4) = acc[im][r];
    __syncthreads();
#pragma unroll
    for (int i = 0; i < 2; i++) {
      int c = i * 256 + tid;
      int rrow = c >> 4, j = c & 15;
      float s = 0.f;
#pragma unroll
      for (int w = 0; w < 4; w++) s += *(const float*)(smem + w * 2048 + rrow * 64 + j * 4);
      partial[((size_t)n * 2048 + rb * 32 + rrow) * 16 + j] = s;
    }
    return;
  }

  int nblk, mblk, n;
  decode_bid(blockIdx.x, nblk, mblk, n);
  const int wm = (wave >> 1) * 64, wn = (wave & 1) * 64;
  const int lrow = lane >> 3, lcol = lane & 7;
  const int swz = (lcol ^ lrow) * 8;
  const int xr = l15 & 7;
  const int arow = tid >> 1, ahalf = (tid & 1) * 32;
  const int arx = arow & 7;

  const float* Ag = graphs + (size_t)(mblk * 128) * 8192 + n * 512;
  const __hip_bfloat16* Bg = W1t + (size_t)n * 262144 + (size_t)(nblk * 128) * 512;

  f32x4 acc[4][4] = {};
  for (int ks = 0; ks < 8; ks++) {
    const int k0 = ks * 64;
    const float* asrc = Ag + (size_t)arow * 8192 + k0 + ahalf;
    float f[32];
#pragma unroll
    for (int j = 0; j < 8; j++) *(float4*)(f + j * 4) = *(const float4*)(asrc + j * 4);
#pragma unroll
    for (int i = 0; i < 4; i++) {
      const int r = i * 32 + wave * 8 + lrow;
      gl2lds16(Bg + (size_t)r * 512 + k0 + swz,
               smem + 16384 + i * 4096 + wave * 1024 + lane * 16);
    }
    __hip_bfloat16 t[32];
#pragma unroll
    for (int e = 0; e < 32; e++) t[e] = __float2bfloat16(f[e]);
    char* abase = smem + arow * 128;
#pragma unroll
    for (int j = 0; j < 4; j++) {
      int c = (ahalf >> 3) + j;
      *(bf16x8*)(abase + ((c ^ arx) * 16)) = *(const bf16x8*)(t + j * 8);
    }
    __syncthreads();
#pragma unroll
    for (int hh = 0; hh < 2; hh++) {
      const int co = ((q + hh * 4) ^ xr) * 16;
      bf16x8 av[4], bv[4];
#pragma unroll
      for (int im = 0; im < 4; im++)
        av[im] = *(const bf16x8*)(smem + (wm + im * 16 + l15) * 128 + co);
#pragma unroll
      for (int in = 0; in < 4; in++)
        bv[in] = *(const bf16x8*)(smem + 16384 + (wn + in * 16 + l15) * 128 + co);
#pragma unroll
      for (int im = 0; im < 4; im++)
#pragma unroll
        for (int in = 0; in < 4; in++)
          acc[im][in] = __builtin_amdgcn_mfma_f32_16x16x32_bf16(av[im], bv[in], acc[im][in], 0, 0, 0);
    }
    __syncthreads();
  }

  float bias[4];
#pragma unroll
  for (int in = 0; in < 4; in++)
    bias[in] = b1[n * 512 + nblk * 128 + wn + in * 16 + l15];
  char* epi = smem + wave * 9216;
#pragma unroll
  for (int im = 0; im < 4; im++)
#pragma unroll
    for (int in = 0; in < 4; in++)
#pragma unroll
      for (int r = 0; r < 4; r++) {
        float v = acc[im][in][r] + bias[in];
        v = fmaxf(v, 0.f);
        int rl = im * 16 + q * 4 + r;
        int cl = in * 16 + l15;
        *(__hip_bfloat16*)(epi + rl * 144 + cl * 2) = __float2bfloat16(v);
      }
  __syncthreads();
  __hip_bfloat16* Hg = h + (size_t)(mblk * 128 + wm) * 8192 + n * 512 + nblk * 128 + wn;
#pragma unroll
  for (int it = 0; it < 8; it++) {
    int rl = it * 8 + (lane >> 3);
    int cl = (lane & 7) * 8;
    bf16x8 v = *(const bf16x8*)(epi + rl * 144 + cl * 2);
    *(bf16x8*)(Hg + (size_t)rl * 8192 + cl) = v;
  }
}

// ------- GEMM2 128^2 (fallback path only) ----------------------------------
__global__ __launch_bounds__(256, 4) void gemm2_kernel(
    const __hip_bfloat16* __restrict__ hbuf,
    const __hip_bfloat16* __restrict__ W2t,
    const float* __restrict__ b2,
    const float* __restrict__ probs,
    float* __restrict__ out) {
  __shared__ char smem[32768];
  const int tid = threadIdx.x, lane = tid & 63, wave = tid >> 6;
  int nblk, mblk, n;
  decode_bid(blockIdx.x, nblk, mblk, n);
  const int wm = (wave >> 1) * 64, wn = (wave & 1) * 64;
  const int q = lane >> 4, l15 = lane & 15;
  const int lrow = lane >> 3, lcol = lane & 7;
  const int swz = (lcol ^ lrow) * 8;
  const int xr = l15 & 7;

  const __hip_bfloat16* Ag = hbuf + (size_t)(mblk * 128) * 8192 + n * 512;
  const __hip_bfloat16* Bg = W2t + (size_t)n * 262144 + (size_t)(nblk * 128) * 512;

  f32x4 acc[4][4] = {};
  for (int ks = 0; ks < 8; ks++) {
    const int k0 = ks * 64;
#pragma unroll
    for (int i = 0; i < 4; i++) {
      const int r = i * 32 + wave * 8 + lrow;
      gl2lds16(Ag + (size_t)r * 8192 + k0 + swz, smem + i * 4096 + wave * 1024 + lane * 16);
      gl2lds16(Bg + (size_t)r * 512 + k0 + swz,
               smem + 16384 + i * 4096 + wave * 1024 + lane * 16);
    }
    __syncthreads();
#pragma unroll
    for (int hh = 0; hh < 2; hh++) {
      const int co = ((q + hh * 4) ^ xr) * 16;
      bf16x8 av[4], bv[4];
#pragma unroll
      for (int im = 0; im < 4; im++)
        av[im] = *(const bf16x8*)(smem + (wm + im * 16 + l15) * 128 + co);
#pragma unroll
      for (int in = 0; in < 4; in++)
        bv[in] = *(const bf16x8*)(smem + 16384 + (wn + in * 16 + l15) * 128 + co);
#pragma unroll
      for (int im = 0; im < 4; im++)
#pragma unroll
        for (int in = 0; in < 4; in++)
          acc[im][in] = __builtin_amdgcn_mfma_f32_16x16x32_bf16(av[im], bv[in], acc[im][in], 0, 0, 0);
    }
    __syncthreads();
  }

  float bias[4];
#pragma unroll
  for (int in = 0; in < 4; in++)
    bias[in] = b2[n * 512 + nblk * 128 + wn + in * 16 + l15];
  float* comb = (float*)smem;
#pragma unroll
  for (int im = 0; im < 4; im++)
#pragma unroll
    for (int r = 0; r < 4; r++) {
      int rl = wm + im * 16 + q * 4 + r;
      float pv = probs[(size_t)(mblk * 128 + rl) * 16 + l15];
#pragma unroll
      for (int in = 0; in < 4; in++) {
        float v = (acc[im][in][r] + bias[in]) * pv;
        v += __shfl_xor(v, 1);
        v += __shfl_xor(v, 2);
        v += __shfl_xor(v, 4);
        v += __shfl_xor(v, 8);
        if (l15 == 0) comb[rl * 8 + (wn >> 4) + in] = v;
      }
    }
  __syncthreads();
  if (tid < 128) {
    float4 v0 = *(const float4*)(comb + tid * 8);
    float4 v1 = *(const float4*)(comb + tid * 8 + 4);
    float* orow = out + (size_t)(mblk * 128 + tid) * 512 + n * 32 + nblk * 8;
    *(float4*)orow = v0;
    *(float4*)(orow + 4) = v1;
  }
}

// ---------------------------------------------------------------------------
extern "C" void kernel_launch(void* const* d_in, const int* in_sizes, int n_in,
                              void* d_out, int out_size, void* d_ws, size_t ws_size,
                              hipStream_t stream) {
  const float* graphs = (const float*)d_in[0];
  const float* W1 = (const float*)d_in[1];
  const float* b1 = (const float*)d_in[2];
  const float* W2 = (const float*)d_in[3];
  const float* b2 = (const float*)d_in[4];
  const float* Wg = (const float*)d_in[5];
  const float* bg = (const float*)d_in[6];
  float* out = (float*)d_out;

  char* ws = (char*)d_ws;
  __hip_bfloat16* W1t = (__hip_bfloat16*)(ws + OFF_W1T);
  __hip_bfloat16* W2t = (__hip_bfloat16*)(ws + OFF_W2T);
  __hip_bfloat16* hb  = (__hip_bfloat16*)(ws + OFF_H);
  float* partial = (float*)(ws + OFF_PART);
  float* probs   = (float*)(ws + OFF_PROB);

  if (ws_size >= WS_NEED_NEW) {
    __hip_bfloat16* gbb = (__hip_bfloat16*)(ws + OFF_GB);
    prep_kernel<<<3072, 256, 0, stream>>>(graphs, Wg, W1, W2, W1t, W2t, gbb, partial);
    gemm1_sm_kernel<<<1032, 256, 0, stream>>>(gbb, W1t, b1, partial, bg, hb,
                                              probs, out + 2048 * 512);
    gemm2_256_kernel<<<256, 512, 0, stream>>>(hb, W2t, b2, probs, out);
  } else {
    transpose_kernel<<<dim3(64, 32), 256, 0, stream>>>(W1, W2, W1t, W2t);
    gemm1_gate_kernel<<<2048, 256, 0, stream>>>(graphs, W1t, Wg, b1, hb, partial);
    softmax_kernel<<<8, 256, 0, stream>>>(partial, bg, probs, out + 2048 * 512);
    gemm2_kernel<<<1024, 256, 0, stream>>>(hb, W2t, b2, probs, out);
  }
}

// Round 13
// 189.487 us; speedup vs baseline: 1.0739x; 1.0739x over previous
//
#include <hip/hip_runtime.h>
#include <hip/hip_bf16.h>

// ---------------------------------------------------------------------------
// GraphExpert: per-node expert MLPs (16 nodes, 2048 batch, 512 hid) + gating.
// fp32 global I/O, bf16 MFMA compute.
// R22 = R18 byte-exact fallback. R20/R21 (epilogue-load hoist) failed the
// container twice with identical source — per pre-committed contingency the
// hoist delta is dropped and the session returns to the best VERIFIED
// configuration (measured 186.7-190.3 us): prep (convert+gate+transpose,
// full A-prefetch) -> gemm1_sm (pure-gl2lds gemm1 + softmax riders) ->
// gemm2 (128^2, 4 blocks/CU). Fallback (ws < 86.1 MB): R11 pipeline.
// Session evidence: 256^2 2-phase (R17) and counted-vmcnt (R19) both null
// vs this structure; prep swizzle fixed conflicts but not time (R15); full
// A-prefetch was the real prep win (R16).
// ---------------------------------------------------------------------------

typedef __attribute__((ext_vector_type(8))) short bf16x8;   // 8 bf16 = 4 VGPRs
typedef __attribute__((ext_vector_type(4))) float f32x4;    // MFMA C/D frag

// workspace layout (bytes)
#define OFF_W1T  (0u)          // bf16 [16][512][512]  (8 MB)
#define OFF_W2T  (8388608u)    // bf16 [16][512][512]  (8 MB)
#define OFF_H    (16777216u)   // bf16 [2048][16][512] (33.55 MB)
#define OFF_PART (50331648u)   // fp32 [16][2048][16]  (2 MB)
#define OFF_PROB (52428800u)   // fp32 [2048][16]      (128 KB)
#define OFF_GB   (52559872u)   // bf16 [2048][16][512] (33.55 MB) — new path only
#define WS_NEED_NEW (86114304ull)

__device__ __forceinline__ void gl2lds16(const void* g, void* l) {
  __builtin_amdgcn_global_load_lds(
      (const __attribute__((address_space(1))) void*)g,
      (__attribute__((address_space(3))) void*)l, 16, 0, 0);
}

__device__ __forceinline__ void cvt16v(const float* __restrict__ src,
                                       bf16x8& lo, bf16x8& hi) {
  float f[16];
  *(float4*)(f + 0)  = *(const float4*)(src + 0);
  *(float4*)(f + 4)  = *(const float4*)(src + 4);
  *(float4*)(f + 8)  = *(const float4*)(src + 8);
  *(float4*)(f + 12) = *(const float4*)(src + 12);
  __hip_bfloat16 t[16];
#pragma unroll
  for (int e = 0; e < 16; e++) t[e] = __float2bfloat16(f[e]);
  lo = *(const bf16x8*)t;
  hi = *(const bf16x8*)(t + 8);
}

// block-id remap: the 4 nblk siblings sharing one A-strip sit at bids
// b, b+8, b+16, b+24 (same bid%8 -> same XCD) for L2 reuse of the A strip.
__device__ __forceinline__ void decode_bid(int bid, int& nblk, int& mblk, int& n) {
  int x8 = bid & 7;
  nblk = (bid >> 3) & 3;
  int pair = (bid >> 5) * 8 + x8; // 0..255
  mblk = pair >> 4;
  n = pair & 15;
}

// ============ PREP: convert_gate (bids<1024) + transpose (bids>=1024) ======
__global__ __launch_bounds__(256, 3) void prep_kernel(
    const float* __restrict__ graphs,
    const float* __restrict__ Wg,
    const float* __restrict__ W1, const float* __restrict__ W2,
    __hip_bfloat16* __restrict__ W1t, __hip_bfloat16* __restrict__ W2t,
    __hip_bfloat16* __restrict__ gb,
    float* __restrict__ partial) {
  __shared__ char smem[49664]; // cg: Aw 4x8256 @0, Bt @33024 (16x1040),
                               // acc staging reuses Bt area after k-loop.
                               // transpose: 9216 B @0.
  const int tid = threadIdx.x, lane = tid & 63, wave = tid >> 6;

  if (blockIdx.x >= 1024) {
    // ================= transpose path =================
    const int t = blockIdx.x - 1024;      // 0..2047
    const int bx = t & 63, by = t >> 6;   // bx 0..63, by 0..31
    const int ht = bx & 7, kt = bx >> 3;
    const int n = by & 15;
    const float* src = (by >> 4) ? W2 : W1;
    __hip_bfloat16* dst = (by >> 4) ? W2t : W1t;
    src += (size_t)n * 262144;
    dst += (size_t)n * 262144;
    const int hq4 = (tid & 15) * 4, kr = tid >> 4;
#pragma unroll
    for (int rr = 0; rr < 4; rr++) {
      const int kl = rr * 16 + kr;
      float4 v = *(const float4*)(src + (size_t)(kt * 64 + kl) * 512 + ht * 64 + hq4);
      __hip_bfloat16 t4[4] = {__float2bfloat16(v.x), __float2bfloat16(v.y),
                              __float2bfloat16(v.z), __float2bfloat16(v.w)};
#pragma unroll
      for (int i = 0; i < 4; i++)
        *(__hip_bfloat16*)(smem + (hq4 + i) * 144 + kl * 2) = t4[i];
    }
    __syncthreads();
    const int c8 = tid & 7, hr = tid >> 3;
#pragma unroll
    for (int rr = 0; rr < 2; rr++) {
      const int hl = rr * 32 + hr;
      bf16x8 v = *(const bf16x8*)(smem + hl * 144 + c8 * 16);
      *(bf16x8*)(dst + (size_t)(ht * 64 + hl) * 512 + kt * 64 + c8 * 8) = v;
    }
    return;
  }

  // ================= convert_gate path (full A prefetch) =================
  const int q = lane >> 4, l15 = lane & 15;
  const int n = blockIdx.x & 15, rb = blockIdx.x >> 4;
  char* Bt = smem + 33024;
  char* Aw = smem + wave * 8256;

  const int arow = lane >> 1, ahalf = (lane & 1) * 16;
  const float* Ag = graphs + (size_t)(rb * 32) * 8192 + n * 512 + wave * 128;

  // FULL prefetch: all 64 fp32 (16 float4) issued before Bt staging.
  // vmcnt retires in order -> Bt's own wait drains these too; one exposed
  // latency for the whole block instead of one per k-step.
  float g[64];
  {
    const float* ap = Ag + (size_t)arow * 8192 + ahalf;
#pragma unroll
    for (int ks = 0; ks < 4; ks++)
#pragma unroll
      for (int j = 0; j < 4; j++)
        *(float4*)(g + ks * 16 + j * 4) = *(const float4*)(ap + ks * 32 + j * 4);
  }

  // Bt staging: Wg n-slice -> bf16, Bt[j][k] row stride 1040 B
#pragma unroll
  for (int i = 0; i < 2; i++) {
    int k = i * 256 + tid;
    const float* wr_ = Wg + (size_t)(n * 512 + k) * 16;
    float f[16];
    *(float4*)(f + 0)  = *(const float4*)(wr_ + 0);
    *(float4*)(f + 4)  = *(const float4*)(wr_ + 4);
    *(float4*)(f + 8)  = *(const float4*)(wr_ + 8);
    *(float4*)(f + 12) = *(const float4*)(wr_ + 12);
#pragma unroll
    for (int j = 0; j < 16; j++)
      *(__hip_bfloat16*)(Bt + j * 1040 + k * 2) = __float2bfloat16(f[j]);
  }
  __syncthreads();

  f32x4 acc[2] = {};
#pragma unroll
  for (int ks = 0; ks < 4; ks++) {
    const float* gc = g + ks * 16;
    __hip_bfloat16 t[16];
#pragma unroll
    for (int e = 0; e < 16; e++) t[e] = __float2bfloat16(gc[e]);
    bf16x8 lo = *(const bf16x8*)t, hi = *(const bf16x8*)(t + 8);
    // logical chunk (16B units within the 256B row): c0 = ks*4 + (lane&1)*2
    // physical chunk = logical ^ (row&7)  — spreads rows across bank groups.
    const int c0 = ks * 4 + (lane & 1) * 2;
    const int rx = arow & 7;
    *(bf16x8*)(Aw + arow * 256 + ((c0 ^ rx) * 16)) = lo;
    *(bf16x8*)(Aw + arow * 256 + (((c0 + 1) ^ rx) * 16)) = hi;
    bf16x8 bv = *(const bf16x8*)(Bt + l15 * 1040 + (wave * 128 + ks * 32 + q * 8) * 2);
#pragma unroll
    for (int im = 0; im < 2; im++) {
      const int ar = im * 16 + l15; // row read by this lane
      bf16x8 av = *(const bf16x8*)(Aw + ar * 256 + (((ks * 4 + q) ^ (ar & 7)) * 16));
      acc[im] = __builtin_amdgcn_mfma_f32_16x16x32_bf16(av, bv, acc[im], 0, 0, 0);
    }
  }
  __syncthreads(); // all waves done reading Bt + writing their Aw

  // acc staging into the (now dead) Bt area: per-wave 2 KB
#pragma unroll
  for (int im = 0; im < 2; im++)
#pragma unroll
    for (int r = 0; r < 4; r++)
      *(float*)(smem + 33024 + wave * 2048 + (im * 16 + q * 4 + r) * 64 + l15 * 4) = acc[im][r];

  // coalesced gb store: 8 rounds; each round stores 8 full rows of 512 bf16
  __hip_bfloat16* gbase = gb + (size_t)(rb * 32) * 8192 + n * 512;
#pragma unroll
  for (int r = 0; r < 8; r++) {
    int u = r * 256 + tid;
    int row = u >> 6, cu = u & 63;
    int ch = (cu & 15) ^ (row & 7); // undo the write-side swizzle
    bf16x8 v = *(const bf16x8*)(smem + (cu >> 4) * 8256 + row * 256 + ch * 16);
    *(bf16x8*)(gbase + (size_t)row * 8192 + cu * 8) = v;
  }
  __syncthreads(); // acc staging visible cross-wave

#pragma unroll
  for (int i = 0; i < 2; i++) {
    int c = i * 256 + tid;
    int rrow = c >> 4, j = c & 15;
    float s = 0.f;
#pragma unroll
    for (int w = 0; w < 4; w++)
      s += *(const float*)(smem + 33024 + w * 2048 + rrow * 64 + j * 4);
    partial[((size_t)n * 2048 + rb * 32 + rrow) * 16 + j] = s;
  }
}

// ============ GEMM1 (bids<1024, pure gl2lds) + softmax (bids>=1024) ========
__global__ __launch_bounds__(256, 4) void gemm1_sm_kernel(
    const __hip_bfloat16* __restrict__ gbuf,
    const __hip_bfloat16* __restrict__ W1t,
    const float* __restrict__ b1,
    const float* __restrict__ partial,
    const float* __restrict__ bg,
    __hip_bfloat16* __restrict__ h,
    float* __restrict__ probs,
    float* __restrict__ probs_out) {
  __shared__ char smem[36864]; // A16K@0, B16K@16384; epi 4x9216@0
  const int tid = threadIdx.x, lane = tid & 63, wave = tid >> 6;

  if (blockIdx.x >= 1024) {
    // ================= softmax path (8 blocks) =================
    const int r = (blockIdx.x - 1024) * 256 + tid; // 0..2047
    float s[16];
#pragma unroll
    for (int j = 0; j < 16; j++) s[j] = 0.f;
    for (int nn = 0; nn < 16; nn++) {
      const float4* p = (const float4*)(partial + ((size_t)nn * 2048 + r) * 16);
#pragma unroll
      for (int c = 0; c < 4; c++) {
        float4 v = p[c];
        s[c * 4 + 0] += v.x; s[c * 4 + 1] += v.y;
        s[c * 4 + 2] += v.z; s[c * 4 + 3] += v.w;
      }
    }
    float mx = -1e30f;
#pragma unroll
    for (int j = 0; j < 16; j++) { s[j] += bg[j]; mx = fmaxf(mx, s[j]); }
    float sum = 0.f;
#pragma unroll
    for (int j = 0; j < 16; j++) { s[j] = __expf(s[j] - mx); sum += s[j]; }
    float inv = 1.f / sum;
#pragma unroll
    for (int j = 0; j < 16; j++) s[j] *= inv;
    float4* pw = (float4*)(probs + (size_t)r * 16);
    float4* ow = (float4*)(probs_out + (size_t)r * 16);
#pragma unroll
    for (int c = 0; c < 4; c++) {
      float4 v = make_float4(s[c*4], s[c*4+1], s[c*4+2], s[c*4+3]);
      pw[c] = v; ow[c] = v;
    }
    return;
  }

  // ================= gemm1 main path =================
  int nblk, mblk, n;
  decode_bid(blockIdx.x, nblk, mblk, n);
  const int wm = (wave >> 1) * 64, wn = (wave & 1) * 64;
  const int q = lane >> 4, l15 = lane & 15;
  const int lrow = lane >> 3, lcol = lane & 7;
  const int swz = (lcol ^ lrow) * 8;
  const int xr = l15 & 7;

  const __hip_bfloat16* Ag = gbuf + (size_t)(mblk * 128) * 8192 + n * 512;
  const __hip_bfloat16* Bg = W1t + (size_t)n * 262144 + (size_t)(nblk * 128) * 512;

  f32x4 acc[4][4] = {};
  for (int ks = 0; ks < 8; ks++) {
    const int k0 = ks * 64;
#pragma unroll
    for (int i = 0; i < 4; i++) {
      const int r = i * 32 + wave * 8 + lrow;
      gl2lds16(Ag + (size_t)r * 8192 + k0 + swz, smem + i * 4096 + wave * 1024 + lane * 16);
      gl2lds16(Bg + (size_t)r * 512 + k0 + swz,
               smem + 16384 + i * 4096 + wave * 1024 + lane * 16);
    }
    __syncthreads();
#pragma unroll
    for (int hh = 0; hh < 2; hh++) {
      const int co = ((q + hh * 4) ^ xr) * 16;
      bf16x8 av[4], bv[4];
#pragma unroll
      for (int im = 0; im < 4; im++)
        av[im] = *(const bf16x8*)(smem + (wm + im * 16 + l15) * 128 + co);
#pragma unroll
      for (int in = 0; in < 4; in++)
        bv[in] = *(const bf16x8*)(smem + 16384 + (wn + in * 16 + l15) * 128 + co);
#pragma unroll
      for (int im = 0; im < 4; im++)
#pragma unroll
        for (int in = 0; in < 4; in++)
          acc[im][in] = __builtin_amdgcn_mfma_f32_16x16x32_bf16(av[im], bv[in], acc[im][in], 0, 0, 0);
    }
    __syncthreads();
  }

  float bias[4];
#pragma unroll
  for (int in = 0; in < 4; in++)
    bias[in] = b1[n * 512 + nblk * 128 + wn + in * 16 + l15];
  char* epi = smem + wave * 9216;
#pragma unroll
  for (int im = 0; im < 4; im++)
#pragma unroll
    for (int in = 0; in < 4; in++)
#pragma unroll
      for (int r = 0; r < 4; r++) {
        float v = acc[im][in][r] + bias[in];
        v = fmaxf(v, 0.f);
        int rl = im * 16 + q * 4 + r;
        int cl = in * 16 + l15;
        *(__hip_bfloat16*)(epi + rl * 144 + cl * 2) = __float2bfloat16(v);
      }
  __syncthreads();
  __hip_bfloat16* Hg = h + (size_t)(mblk * 128 + wm) * 8192 + n * 512 + nblk * 128 + wn;
#pragma unroll
  for (int it = 0; it < 8; it++) {
    int rl = it * 8 + (lane >> 3);
    int cl = (lane & 7) * 8;
    bf16x8 v = *(const bf16x8*)(epi + rl * 144 + cl * 2);
    *(bf16x8*)(Hg + (size_t)rl * 8192 + cl) = v;
  }
}

// ----------- standalone kernels for the ws-fallback path (R11) -------------
__global__ __launch_bounds__(256) void transpose_kernel(
    const float* __restrict__ W1, const float* __restrict__ W2,
    __hip_bfloat16* __restrict__ W1t, __hip_bfloat16* __restrict__ W2t) {
  __shared__ char smem[9216];
  const int bx = blockIdx.x;
  const int ht = bx & 7, kt = bx >> 3;
  const int n = blockIdx.y & 15;
  const float* src = (blockIdx.y >> 4) ? W2 : W1;
  __hip_bfloat16* dst = (blockIdx.y >> 4) ? W2t : W1t;
  src += (size_t)n * 262144;
  dst += (size_t)n * 262144;
  const int tid = threadIdx.x;
  const int hq4 = (tid & 15) * 4, kr = tid >> 4;
#pragma unroll
  for (int rr = 0; rr < 4; rr++) {
    const int kl = rr * 16 + kr;
    float4 v = *(const float4*)(src + (size_t)(kt * 64 + kl) * 512 + ht * 64 + hq4);
    __hip_bfloat16 t4[4] = {__float2bfloat16(v.x), __float2bfloat16(v.y),
                            __float2bfloat16(v.z), __float2bfloat16(v.w)};
#pragma unroll
    for (int i = 0; i < 4; i++)
      *(__hip_bfloat16*)(smem + (hq4 + i) * 144 + kl * 2) = t4[i];
  }
  __syncthreads();
  const int c8 = tid & 7, hr = tid >> 3;
#pragma unroll
  for (int rr = 0; rr < 2; rr++) {
    const int hl = rr * 32 + hr;
    bf16x8 v = *(const bf16x8*)(smem + hl * 144 + c8 * 16);
    *(bf16x8*)(dst + (size_t)(ht * 64 + hl) * 512 + kt * 64 + c8 * 8) = v;
  }
}

__global__ void softmax_kernel(const float* __restrict__ partial,
                               const float* __restrict__ bg,
                               float* __restrict__ probs,
                               float* __restrict__ probs_out) {
  const int r = blockIdx.x * 256 + threadIdx.x;
  float s[16];
#pragma unroll
  for (int j = 0; j < 16; j++) s[j] = 0.f;
  for (int nn = 0; nn < 16; nn++) {
    const float4* p = (const float4*)(partial + ((size_t)nn * 2048 + r) * 16);
#pragma unroll
    for (int c = 0; c < 4; c++) {
      float4 v = p[c];
      s[c * 4 + 0] += v.x; s[c * 4 + 1] += v.y;
      s[c * 4 + 2] += v.z; s[c * 4 + 3] += v.w;
    }
  }
  float mx = -1e30f;
#pragma unroll
  for (int j = 0; j < 16; j++) { s[j] += bg[j]; mx = fmaxf(mx, s[j]); }
  float sum = 0.f;
#pragma unroll
  for (int j = 0; j < 16; j++) { s[j] = __expf(s[j] - mx); sum += s[j]; }
  float inv = 1.f / sum;
#pragma unroll
  for (int j = 0; j < 16; j++) s[j] *= inv;
  float4* pw = (float4*)(probs + (size_t)r * 16);
  float4* ow = (float4*)(probs_out + (size_t)r * 16);
#pragma unroll
  for (int c = 0; c < 4; c++) {
    float4 v = make_float4(s[c*4], s[c*4+1], s[c*4+2], s[c*4+3]);
    pw[c] = v; ow[c] = v;
  }
}

__global__ __launch_bounds__(256, 4) void gemm1_gate_kernel(
    const float* __restrict__ graphs,
    const __hip_bfloat16* __restrict__ W1t,
    const float* __restrict__ Wg,
    const float* __restrict__ b1,
    __hip_bfloat16* __restrict__ h,
    float* __restrict__ partial) {
  __shared__ char smem[36864];
  const int tid = threadIdx.x, lane = tid & 63, wave = tid >> 6;
  const int q = lane >> 4, l15 = lane & 15;

  if (blockIdx.x >= 1024) {
    const int gbid = blockIdx.x - 1024;
    const int n = gbid & 15, rb = gbid >> 4;
    char* Bt = smem + 8192;
#pragma unroll
    for (int i = 0; i < 2; i++) {
      int k = i * 256 + tid;
      const float* wr_ = Wg + (size_t)(n * 512 + k) * 16;
      float f[16];
      *(float4*)(f + 0)  = *(const float4*)(wr_ + 0);
      *(float4*)(f + 4)  = *(const float4*)(wr_ + 4);
      *(float4*)(f + 8)  = *(const float4*)(wr_ + 8);
      *(float4*)(f + 12) = *(const float4*)(wr_ + 12);
#pragma unroll
      for (int j = 0; j < 16; j++)
        *(__hip_bfloat16*)(Bt + j * 1040 + k * 2) = __float2bfloat16(f[j]);
    }
    __syncthreads();

    const int arow = lane >> 1, ahalf = (lane & 1) * 16;
    const float* Ag = graphs + (size_t)(rb * 32) * 8192 + n * 512 + wave * 128;
    char* Aw = smem + wave * 2048;

    f32x4 acc[2] = {};
    for (int ks = 0; ks < 4; ks++) {
      bf16x8 lo, hi;
      cvt16v(Ag + (size_t)arow * 8192 + ks * 32 + ahalf, lo, hi);
      char* d = Aw + arow * 64 + ahalf * 2;
      *(bf16x8*)d = lo;
      *(bf16x8*)(d + 16) = hi;
      bf16x8 bv = *(const bf16x8*)(Bt + l15 * 1040 + (wave * 128 + ks * 32 + q * 8) * 2);
#pragma unroll
      for (int im = 0; im < 2; im++) {
        bf16x8 av = *(const bf16x8*)(Aw + (im * 16 + l15) * 64 + q * 16);
        acc[im] = __builtin_amdgcn_mfma_f32_16x16x32_bf16(av, bv, acc[im], 0, 0, 0);
      }
    }
#pragma unroll
    for (int im = 0; im < 2; im++)
#pragma unroll
      for (int r = 0; r < 4; r++)
        *(float*)(smem + wave * 2048 + (im * 16 + q * 4 + r) * 64 + l15 * 4) = acc[im][r];
    __syncthreads();
#pragma unroll
    for (int i = 0; i < 2; i++) {
      int c = i * 256 + tid;
      int rrow = c >> 4, j = c & 15;
      float s = 0.f;
#pragma unroll
      for (int w = 0; w < 4; w++) s += *(const float*)(smem + w * 2048 + rrow * 64 + j * 4);
      partial[((size_t)n * 2048 + rb * 32 + rrow) * 16 + j] = s;
    }
    return;
  }

  int nblk, mblk, n;
  decode_bid(blockIdx.x, nblk, mblk, n);
  const int wm = (wave >> 1) * 64, wn = (wave & 1) * 64;
  const int lrow = lane >> 3, lcol = lane & 7;
  const int swz = (lcol ^ lrow) * 8;
  const int xr = l15 & 7;
  const int arow = tid >> 1, ahalf = (tid & 1) * 32;
  const int arx = arow & 7;

  const float* Ag = graphs + (size_t)(mblk * 128) * 8192 + n * 512;
  const __hip_bfloat16* Bg = W1t + (size_t)n * 262144 + (size_t)(nblk * 128) * 512;

  f32x4 acc[4][4] = {};
  for (int ks = 0; ks < 8; ks++) {
    const int k0 = ks * 64;
    const float* asrc = Ag + (size_t)arow * 8192 + k0 + ahalf;
    float f[32];
#pragma unroll
    for (int j = 0; j < 8; j++) *(float4*)(f + j * 4) = *(const float4*)(asrc + j * 4);
#pragma unroll
    for (int i = 0; i < 4; i++) {
      const int r = i * 32 + wave * 8 + lrow;
      gl2lds16(Bg + (size_t)r * 512 + k0 + swz,
               smem + 16384 + i * 4096 + wave * 1024 + lane * 16);
    }
    __hip_bfloat16 t[32];
#pragma unroll
    for (int e = 0; e < 32; e++) t[e] = __float2bfloat16(f[e]);
    char* abase = smem + arow * 128;
#pragma unroll
    for (int j = 0; j < 4; j++) {
      int c = (ahalf >> 3) + j;
      *(bf16x8*)(abase + ((c ^ arx) * 16)) = *(const bf16x8*)(t + j * 8);
    }
    __syncthreads();
#pragma unroll
    for (int hh = 0; hh < 2; hh++) {
      const int co = ((q + hh * 4) ^ xr) * 16;
      bf16x8 av[4], bv[4];
#pragma unroll
      for (int im = 0; im < 4; im++)
        av[im] = *(const bf16x8*)(smem + (wm + im * 16 + l15) * 128 + co);
#pragma unroll
      for (int in = 0; in < 4; in++)
        bv[in] = *(const bf16x8*)(smem + 16384 + (wn + in * 16 + l15) * 128 + co);
#pragma unroll
      for (int im = 0; im < 4; im++)
#pragma unroll
        for (int in = 0; in < 4; in++)
          acc[im][in] = __builtin_amdgcn_mfma_f32_16x16x32_bf16(av[im], bv[in], acc[im][in], 0, 0, 0);
    }
    __syncthreads();
  }

  float bias[4];
#pragma unroll
  for (int in = 0; in < 4; in++)
    bias[in] = b1[n * 512 + nblk * 128 + wn + in * 16 + l15];
  char* epi = smem + wave * 9216;
#pragma unroll
  for (int im = 0; im < 4; im++)
#pragma unroll
    for (int in = 0; in < 4; in++)
#pragma unroll
      for (int r = 0; r < 4; r++) {
        float v = acc[im][in][r] + bias[in];
        v = fmaxf(v, 0.f);
        int rl = im * 16 + q * 4 + r;
        int cl = in * 16 + l15;
        *(__hip_bfloat16*)(epi + rl * 144 + cl * 2) = __float2bfloat16(v);
      }
  __syncthreads();
  __hip_bfloat16* Hg = h + (size_t)(mblk * 128 + wm) * 8192 + n * 512 + nblk * 128 + wn;
#pragma unroll
  for (int it = 0; it < 8; it++) {
    int rl = it * 8 + (lane >> 3);
    int cl = (lane & 7) * 8;
    bf16x8 v = *(const bf16x8*)(epi + rl * 144 + cl * 2);
    *(bf16x8*)(Hg + (size_t)rl * 8192 + cl) = v;
  }
}

// ---------------- GEMM2 + weighted combine (fp32 out) — R4-proven -----------
__global__ __launch_bounds__(256, 4) void gemm2_kernel(
    const __hip_bfloat16* __restrict__ hbuf,
    const __hip_bfloat16* __restrict__ W2t,
    const float* __restrict__ b2,
    const float* __restrict__ probs,
    float* __restrict__ out) {
  __shared__ char smem[32768];
  const int tid = threadIdx.x, lane = tid & 63, wave = tid >> 6;
  int nblk, mblk, n;
  decode_bid(blockIdx.x, nblk, mblk, n);
  const int wm = (wave >> 1) * 64, wn = (wave & 1) * 64;
  const int q = lane >> 4, l15 = lane & 15;
  const int lrow = lane >> 3, lcol = lane & 7;
  const int swz = (lcol ^ lrow) * 8;
  const int xr = l15 & 7;

  const __hip_bfloat16* Ag = hbuf + (size_t)(mblk * 128) * 8192 + n * 512;
  const __hip_bfloat16* Bg = W2t + (size_t)n * 262144 + (size_t)(nblk * 128) * 512;

  f32x4 acc[4][4] = {};
  for (int ks = 0; ks < 8; ks++) {
    const int k0 = ks * 64;
#pragma unroll
    for (int i = 0; i < 4; i++) {
      const int r = i * 32 + wave * 8 + lrow;
      gl2lds16(Ag + (size_t)r * 8192 + k0 + swz, smem + i * 4096 + wave * 1024 + lane * 16);
      gl2lds16(Bg + (size_t)r * 512 + k0 + swz,
               smem + 16384 + i * 4096 + wave * 1024 + lane * 16);
    }
    __syncthreads();
#pragma unroll
    for (int hh = 0; hh < 2; hh++) {
      const int co = ((q + hh * 4) ^ xr) * 16;
      bf16x8 av[4], bv[4];
#pragma unroll
      for (int im = 0; im < 4; im++)
        av[im] = *(const bf16x8*)(smem + (wm + im * 16 + l15) * 128 + co);
#pragma unroll
      for (int in = 0; in < 4; in++)
        bv[in] = *(const bf16x8*)(smem + 16384 + (wn + in * 16 + l15) * 128 + co);
#pragma unroll
      for (int im = 0; im < 4; im++)
#pragma unroll
        for (int in = 0; in < 4; in++)
          acc[im][in] = __builtin_amdgcn_mfma_f32_16x16x32_bf16(av[im], bv[in], acc[im][in], 0, 0, 0);
    }
    __syncthreads();
  }

  float bias[4];
#pragma unroll
  for (int in = 0; in < 4; in++)
    bias[in] = b2[n * 512 + nblk * 128 + wn + in * 16 + l15];
  float* comb = (float*)smem; // [128][8] fp32 (staging LDS reused)
#pragma unroll
  for (int im = 0; im < 4; im++)
#pragma unroll
    for (int r = 0; r < 4; r++) {
      int rl = wm + im * 16 + q * 4 + r;
      float pv = probs[(size_t)(mblk * 128 + rl) * 16 + l15];
#pragma unroll
      for (int in = 0; in < 4; in++) {
        float v = (acc[im][in][r] + bias[in]) * pv;
        v += __shfl_xor(v, 1);
        v += __shfl_xor(v, 2);
        v += __shfl_xor(v, 4);
        v += __shfl_xor(v, 8);
        if (l15 == 0) comb[rl * 8 + (wn >> 4) + in] = v;
      }
    }
  __syncthreads();
  if (tid < 128) {
    float4 v0 = *(const float4*)(comb + tid * 8);
    float4 v1 = *(const float4*)(comb + tid * 8 + 4);
    float* orow = out + (size_t)(mblk * 128 + tid) * 512 + n * 32 + nblk * 8;
    *(float4*)orow = v0;
    *(float4*)(orow + 4) = v1;
  }
}

// ---------------------------------------------------------------------------
extern "C" void kernel_launch(void* const* d_in, const int* in_sizes, int n_in,
                              void* d_out, int out_size, void* d_ws, size_t ws_size,
                              hipStream_t stream) {
  const float* graphs = (const float*)d_in[0];
  const float* W1 = (const float*)d_in[1];
  const float* b1 = (const float*)d_in[2];
  const float* W2 = (const float*)d_in[3];
  const float* b2 = (const float*)d_in[4];
  const float* Wg = (const float*)d_in[5];
  const float* bg = (const float*)d_in[6];
  float* out = (float*)d_out;

  char* ws = (char*)d_ws;
  __hip_bfloat16* W1t = (__hip_bfloat16*)(ws + OFF_W1T);
  __hip_bfloat16* W2t = (__hip_bfloat16*)(ws + OFF_W2T);
  __hip_bfloat16* hb  = (__hip_bfloat16*)(ws + OFF_H);
  float* partial = (float*)(ws + OFF_PART);
  float* probs   = (float*)(ws + OFF_PROB);

  if (ws_size >= WS_NEED_NEW) {
    __hip_bfloat16* gbb = (__hip_bfloat16*)(ws + OFF_GB);
    prep_kernel<<<3072, 256, 0, stream>>>(graphs, Wg, W1, W2, W1t, W2t, gbb, partial);
    gemm1_sm_kernel<<<1032, 256, 0, stream>>>(gbb, W1t, b1, partial, bg, hb,
                                              probs, out + 2048 * 512);
  } else {
    transpose_kernel<<<dim3(64, 32), 256, 0, stream>>>(W1, W2, W1t, W2t);
    gemm1_gate_kernel<<<2048, 256, 0, stream>>>(graphs, W1t, Wg, b1, hb, partial);
    softmax_kernel<<<8, 256, 0, stream>>>(partial, bg, probs, out + 2048 * 512);
  }
  gemm2_kernel<<<1024, 256, 0, stream>>>(hb, W2t, b2, probs, out);
}